// Round 14
// baseline (26.927 us; speedup 1.0000x reference)
//
#include <hip/hip_runtime.h>

// CTC batch cost (Keras, blank=C-1). B=1024, T=256, C=128, L=48, S=97.
// R14: async producer. wave1 issues global_load_lds (direct HBM/L3 -> LDS,
// no VGPR round trip), 3 chunks (24 insts) in flight, COUNTED vmcnt handshake
// (never 0 until tail). wave0 consumer = R10 path: ds_read label column +
// blank column per row, DP + immediate 2^-e rescale (R8-R13 numerics).
// LDS ring 4 x 8KB = 32KB -> 4 blocks/CU preserved.

#define TT 256
#define CC 128
#define LL 48
#define CH 16          // rows per chunk (8 KB)
#define NC (TT / CH)   // 16 chunks

template<int CTRL>
__device__ __forceinline__ float dpp_mv(float x) {
    union { float f; int i; } u, r;
    u.f = x;
    r.i = __builtin_amdgcn_update_dpp(0, u.i, CTRL, 0xF, 0xF, false); // invalid lanes -> 0
    return r.f;
}
__device__ __forceinline__ float rdlane(float x, int l) {
    union { float f; int i; } u, r;
    u.f = x;
    r.i = __builtin_amdgcn_readlane(u.i, l);
    return r.f;
}

// Direct global->LDS DMA: 64 lanes x 16B = 1 KB per instruction.
// LDS dest = uniform base + lane*16 (linear); global src per-lane.
__device__ __forceinline__ void gload_lds16(const float* g, float* l) {
    __builtin_amdgcn_global_load_lds(
        (const __attribute__((address_space(1))) unsigned int*)(const void*)g,
        (__attribute__((address_space(3))) unsigned int*)(void*)l,
        16, 0, 0);
}

__global__ __launch_bounds__(128) void ctc_fwd_v14(
    const float* __restrict__ y,       // [B, T, C]
    const int* __restrict__ labels,    // [B, L]
    float* __restrict__ out)           // [B]
{
    __shared__ float ring[4][CH * CC];         // 4 x 8 KB = 32 KB (raw rows)
    const int lane = threadIdx.x & 63;
    const int w = threadIdx.x >> 6;            // 0 = consumer, 1 = producer
    const int b = blockIdx.x;
    const float EPS = 1e-7f;

    if (w == 1) {
        // ---------------- producer: pure issue engine ----------------
        // NO other vmem ops in this branch: vmcnt counts only the DMAs.
        const float* yb = y + (size_t)b * TT * CC + lane * 4;   // 16B per lane

#define GISSUE(c_) do {                                                   \
    const float* _g = yb + (size_t)(c_) * (CH * CC);                      \
    float* _l = ring[(c_) & 3];                                           \
    _Pragma("unroll")                                                     \
    for (int _k = 0; _k < 8; ++_k)                                        \
        gload_lds16(_g + _k * 256, _l + _k * 256);   /* 1 KB each */      \
    } while (0)

#define SB __builtin_amdgcn_sched_barrier(0)
#define HANDSHAKE(wstr) do {                                              \
    asm volatile("s_waitcnt " wstr ::: "memory");                         \
    SB;                                                                   \
    __builtin_amdgcn_s_barrier();                                         \
    SB;                                                                   \
    } while (0)

        GISSUE(0); GISSUE(1); GISSUE(2);            // 24 in flight
        HANDSHAKE("vmcnt(16)"); GISSUE(3);          // c=0
        HANDSHAKE("vmcnt(16)"); GISSUE(4);          // c=1
        HANDSHAKE("vmcnt(16)"); GISSUE(5);          // c=2
        HANDSHAKE("vmcnt(16)"); GISSUE(6);          // c=3
        HANDSHAKE("vmcnt(16)"); GISSUE(7);          // c=4
        HANDSHAKE("vmcnt(16)"); GISSUE(8);          // c=5
        HANDSHAKE("vmcnt(16)"); GISSUE(9);          // c=6
        HANDSHAKE("vmcnt(16)"); GISSUE(10);         // c=7
        HANDSHAKE("vmcnt(16)"); GISSUE(11);         // c=8
        HANDSHAKE("vmcnt(16)"); GISSUE(12);         // c=9
        HANDSHAKE("vmcnt(16)"); GISSUE(13);         // c=10
        HANDSHAKE("vmcnt(16)"); GISSUE(14);         // c=11
        HANDSHAKE("vmcnt(16)"); GISSUE(15);         // c=12
        HANDSHAKE("vmcnt(16)");                     // c=13
        HANDSHAKE("vmcnt(8)");                      // c=14
        HANDSHAKE("vmcnt(0)");                      // c=15
#undef GISSUE
#undef HANDSHAKE
    } else {
        // ---------------- consumer ----------------
        int lab = CC - 1;                              // lanes >= LL carry blank
        if (lane < LL) lab = labels[b * LL + lane];
        const int labprev = __shfl_up(lab, 1);
        const float csf = ((lane > 0) && (lane < LL) && (lab != labprev)) ? 1.0f : 0.0f;

        float a0 = (lane == 0) ? 1.0f : 0.0f;          // uniform t=0 update -> alpha0
        float a1 = 0.0f;
        int lg = 0;

#define STEP(plv, pbv) do {                                               \
    const float _pp = dpp_mv<0x138>(a1);   /* wave_shr:1 -> a1[l-1] */    \
    const float _a0o = a0;                                                \
    a0 = (_a0o + _pp) * (pbv);                                            \
    a1 = (a1 + _a0o + csf * _pp) * (plv);                                 \
    } while (0)

#define RESCALE do {                                                      \
    float _m = fmaxf(a0, a1);                                             \
    _m = fmaxf(_m, dpp_mv<0x111>(_m));   /* row_shr:1 */                  \
    _m = fmaxf(_m, dpp_mv<0x112>(_m));   /* row_shr:2 */                  \
    _m = fmaxf(_m, dpp_mv<0x114>(_m));   /* row_shr:4 */                  \
    _m = fmaxf(_m, dpp_mv<0x118>(_m));   /* row_shr:8 */                  \
    _m = fmaxf(_m, dpp_mv<0x142>(_m));   /* row_bcast:15 */               \
    _m = fmaxf(_m, dpp_mv<0x143>(_m));   /* row_bcast:31 -> lane63 */     \
    const float _mm = rdlane(_m, 63);                                     \
    int _e; (void)frexpf(_mm, &_e);                                       \
    a0 = ldexpf(a0, -_e);                                                 \
    a1 = ldexpf(a1, -_e);                                                 \
    lg += _e;                                                             \
    } while (0)

#define CITER(c_) do {                                                    \
    __builtin_amdgcn_s_barrier();        /* chunk c_ landed in LDS */     \
    __builtin_amdgcn_sched_barrier(0);                                    \
    const float* _s = ring[(c_) & 3];                                     \
    float _pl[CH], _pb[CH];                                               \
    _Pragma("unroll")                                                     \
    for (int _r = 0; _r < CH; ++_r) {                                     \
        _pl[_r] = _s[_r * CC + lab] + EPS;        /* per-lane column */   \
        _pb[_r] = _s[_r * CC + (CC - 1)] + EPS;   /* broadcast (blank) */ \
    }                                                                     \
    _Pragma("unroll")                                                     \
    for (int _r = 0; _r < CH; ++_r) {                                     \
        STEP(_pl[_r], _pb[_r]);                                           \
        if ((_r & 7) == 7) RESCALE;                                       \
    } } while (0)

        CITER(0);  CITER(1);  CITER(2);  CITER(3);
        CITER(4);  CITER(5);  CITER(6);  CITER(7);
        CITER(8);  CITER(9);  CITER(10); CITER(11);
        CITER(12); CITER(13); CITER(14); CITER(15);

        // loss = -( log(alpha[95] + alpha[96]) + lg*ln2 )
        const float v95 = rdlane(a1, 47);
        const float v96 = rdlane(a0, 48);
        if (lane == 0) {
            const float s = fmaxf(v95 + v96, 1e-37f);
            out[b] = -(__logf(s) + (float)lg * 0.69314718056f);
        }
#undef STEP
#undef RESCALE
#undef CITER
    }
}

extern "C" void kernel_launch(void* const* d_in, const int* in_sizes, int n_in,
                              void* d_out, int out_size, void* d_ws, size_t ws_size,
                              hipStream_t stream) {
    const float* y = (const float*)d_in[0];
    const int* labels = (const int*)d_in[1];
    float* out = (float*)d_out;
    const int B = in_sizes[0] / (TT * CC);   // 1024
    ctc_fwd_v14<<<B, 128, 0, stream>>>(y, labels, out);
}